// Round 1
// baseline (180.053 us; speedup 1.0000x reference)
//
#include <hip/hip_runtime.h>
#include <hip/hip_bf16.h>

#define BN 4
#define TT 4096
#define SS 4096
#define CC 1024
#define HS 64

typedef __bf16 bf16x8 __attribute__((ext_vector_type(8)));
typedef __bf16 bf16x4 __attribute__((ext_vector_type(4)));
typedef __bf16 bf16x2 __attribute__((ext_vector_type(2)));
typedef float  f32x4  __attribute__((ext_vector_type(4)));

#define MFMA16(A, B, C) __builtin_amdgcn_mfma_f32_16x16x32_bf16((A), (B), (C), 0, 0, 0)

// ---------------- prep: W[1024][64] fp32 -> WT[64][1024] bf16 (Wq scaled by 0.125) ----
__global__ __launch_bounds__(256) void prep_wt(const float* __restrict__ Wq,
                                               const float* __restrict__ Wk,
                                               const float* __restrict__ Wv,
                                               __bf16* __restrict__ wt) {
    int idx = blockIdx.x * 256 + threadIdx.x;   // 3*65536 total
    int mat = idx >> 16;
    int e   = idx & 65535;
    int d   = e >> 10;
    int kk  = e & 1023;
    const float* W = (mat == 0) ? Wq : (mat == 1 ? Wk : Wv);
    float v = W[kk * HS + d];
    if (mat == 0) v *= 0.125f;                  // fold HS^-0.5 into Wq exactly (pow2)
    wt[idx] = (__bf16)v;                        // wt[mat][d][kk]
}

// ---------------- fused QKV projection -----------------------------------------------
// blockIdx: [0,256) -> q from x, [256,512) -> k from enc, [512,768) -> v (transposed) from enc
__global__ __launch_bounds__(256) void proj_qkv(const float* __restrict__ x,
                                                const float* __restrict__ enc,
                                                const __bf16* __restrict__ wt,
                                                __bf16* __restrict__ qb,
                                                __bf16* __restrict__ kb,
                                                __bf16* __restrict__ vt) {
    __shared__ __bf16 Alds[64 * 56];            // 64 rows x 32 k, stride 56 (16B aligned, low conflict)
    int tid = threadIdx.x;
    int w = tid >> 6, l = tid & 63, lq = l >> 4, lm = l & 15;
    int mat  = blockIdx.x >> 8;
    int row0 = (blockIdx.x & 255) * 64;
    const float*  src = (mat == 0) ? x : enc;   // [16384][1024]
    const __bf16* wtm = wt + mat * (HS * CC);

    int sr = tid >> 2;                          // staging row 0..63
    int sc = (tid & 3) * 8;                     // staging col (k) 0..24
    const float* srow = src + (size_t)(row0 + sr) * CC + sc;

    f32x4 acc[4];
    #pragma unroll
    for (int i = 0; i < 4; i++) acc[i] = (f32x4){0.f, 0.f, 0.f, 0.f};

    for (int kk = 0; kk < CC; kk += 32) {
        float4 f0 = *(const float4*)(srow + kk);
        float4 f1 = *(const float4*)(srow + kk + 4);
        bf16x8 a;
        a[0] = (__bf16)f0.x; a[1] = (__bf16)f0.y; a[2] = (__bf16)f0.z; a[3] = (__bf16)f0.w;
        a[4] = (__bf16)f1.x; a[5] = (__bf16)f1.y; a[6] = (__bf16)f1.z; a[7] = (__bf16)f1.w;
        *(bf16x8*)&Alds[sr * 56 + sc] = a;
        __syncthreads();
        bf16x8 af = *(const bf16x8*)&Alds[(w * 16 + lm) * 56 + lq * 8];
        #pragma unroll
        for (int nt = 0; nt < 4; nt++) {
            bf16x8 bf = *(const bf16x8*)(wtm + (size_t)(nt * 16 + lm) * CC + kk + lq * 8);
            acc[nt] = MFMA16(af, bf, acc[nt]);
        }
        __syncthreads();
    }

    // D layout: col(n=d)=lane&15, row(m=src row)=(lane>>4)*4+r
    if (mat < 2) {
        __bf16* outb = (mat == 0) ? qb : kb;    // row-major [16384][64]
        #pragma unroll
        for (int nt = 0; nt < 4; nt++)
            #pragma unroll
            for (int r = 0; r < 4; r++)
                outb[(size_t)(row0 + w * 16 + lq * 4 + r) * HS + nt * 16 + lm] = (__bf16)acc[nt][r];
    } else {
        // vt[b][d][s], 4 consecutive s per lane -> 8B store
        int rg = row0 + w * 16 + lq * 4;
        int bb = rg >> 12, s = rg & 4095;
        #pragma unroll
        for (int nt = 0; nt < 4; nt++) {
            bf16x4 pk = { (__bf16)acc[nt][0], (__bf16)acc[nt][1],
                          (__bf16)acc[nt][2], (__bf16)acc[nt][3] };
            *(bf16x4*)(vt + ((size_t)bb * HS + nt * 16 + lm) * SS + s) = pk;
        }
    }
}

// ---------------- flash attention (no-max softmax: logits are tiny) -------------------
// grid 256: b = bid>>6, t-block = (bid&63)*64; 4 waves x 16 q-rows; KVBLK = 32
__global__ __launch_bounds__(256) void attn(const __bf16* __restrict__ qb,
                                            const __bf16* __restrict__ kb,
                                            const __bf16* __restrict__ vt,
                                            float* __restrict__ out) {
    __shared__ __bf16 Plds[4][16 * 56];         // per-wave P^T relayout buffer
    int tid = threadIdx.x, w = tid >> 6, l = tid & 63, lq = l >> 4, lm = l & 15;
    int b = blockIdx.x >> 6, tb = blockIdx.x & 63;
    int t0 = tb * 64 + w * 16;

    // Q^T B-frag: lane holds q[t=lm+t0][d=lq*8+j] (q already scaled by 1/8 via Wq)
    const __bf16* qrow = qb + (size_t)(b * TT + t0 + lm) * HS + lq * 8;
    bf16x8 qf0 = *(const bf16x8*)(qrow);
    bf16x8 qf1 = *(const bf16x8*)(qrow + 32);

    const __bf16* kbp = kb + (size_t)b * SS * HS + lm * HS + lq * 8;
    const __bf16* vbp = vt + (size_t)b * HS * SS + lm * SS + lq * 8;

    f32x4 zero = {0.f, 0.f, 0.f, 0.f};
    f32x4 acc[4];
    #pragma unroll
    for (int i = 0; i < 4; i++) acc[i] = zero;
    float lsum = 0.f;
    __bf16* pl = &Plds[w][0];

    for (int s0 = 0; s0 < SS; s0 += 32) {
        // K A-frags: lane holds k[s0+lm(+16)][d=lq*8+j], d-step 0/1
        const __bf16* kp = kbp + (size_t)s0 * HS;
        bf16x8 ka0 = *(const bf16x8*)(kp);
        bf16x8 ka1 = *(const bf16x8*)(kp + 32);
        bf16x8 kc0 = *(const bf16x8*)(kp + 16 * HS);
        bf16x8 kc1 = *(const bf16x8*)(kp + 16 * HS + 32);

        // S^T[s_local][t]: row=(lq*4+r)=s_local, col=lm=t
        f32x4 st0 = MFMA16(ka0, qf0, zero); st0 = MFMA16(ka1, qf1, st0);
        f32x4 st1 = MFMA16(kc0, qf0, zero); st1 = MFMA16(kc1, qf1, st1);

        float p0 = __expf(st0[0]), p1 = __expf(st0[1]), p2 = __expf(st0[2]), p3 = __expf(st0[3]);
        float p4 = __expf(st1[0]), p5 = __expf(st1[1]), p6 = __expf(st1[2]), p7 = __expf(st1[3]);
        lsum += ((p0 + p1) + (p2 + p3)) + ((p4 + p5) + (p6 + p7));

        // relayout P^T[s][t] -> PV B-frag via wave-private LDS: row=t (stride 56), col=s_local
        bf16x2 w0 = {(__bf16)p0, (__bf16)p1};
        bf16x2 w1 = {(__bf16)p2, (__bf16)p3};
        bf16x2 w2 = {(__bf16)p4, (__bf16)p5};
        bf16x2 w3 = {(__bf16)p6, (__bf16)p7};
        *(bf16x2*)&pl[lm * 56 + lq * 4]          = w0;
        *(bf16x2*)&pl[lm * 56 + lq * 4 + 2]      = w1;
        *(bf16x2*)&pl[lm * 56 + 16 + lq * 4]     = w2;
        *(bf16x2*)&pl[lm * 56 + 16 + lq * 4 + 2] = w3;
        bf16x8 pf = *(const bf16x8*)&pl[lm * 56 + lq * 8];   // B[k=s][n=t]

        // out^T[d][t] += V^T[d][s] * P^T[s][t]
        #pragma unroll
        for (int mt = 0; mt < 4; mt++) {
            bf16x8 vf = *(const bf16x8*)(vbp + (size_t)mt * 16 * SS + s0);
            acc[mt] = MFMA16(vf, pf, acc[mt]);
        }
    }

    lsum += __shfl_xor(lsum, 16, 64);
    lsum += __shfl_xor(lsum, 32, 64);
    float inv = 1.0f / lsum;

    float* orow = out + (size_t)(b * TT + t0 + lm) * HS;
    #pragma unroll
    for (int mt = 0; mt < 4; mt++) {
        f32x4 v = acc[mt] * inv;
        *(float4*)(orow + mt * 16 + lq * 4) = *(float4*)&v;
    }
}

// ---------------- launcher ------------------------------------------------------------
extern "C" void kernel_launch(void* const* d_in, const int* in_sizes, int n_in,
                              void* d_out, int out_size, void* d_ws, size_t ws_size,
                              hipStream_t stream) {
    (void)in_sizes; (void)n_in; (void)out_size; (void)ws_size;
    const float* x   = (const float*)d_in[0];
    const float* enc = (const float*)d_in[1];
    const float* Wq  = (const float*)d_in[2];
    const float* Wk  = (const float*)d_in[3];
    const float* Wv  = (const float*)d_in[4];
    float* out = (float*)d_out;

    char* ws = (char*)d_ws;
    __bf16* wt = (__bf16*)ws;                              // 393216 B
    __bf16* qbuf = (__bf16*)(ws + 393216);                 // 2 MB
    __bf16* kbuf = (__bf16*)(ws + 393216 + 2097152);       // 2 MB
    __bf16* vbuf = (__bf16*)(ws + 393216 + 2 * 2097152);   // 2 MB

    hipLaunchKernelGGL(prep_wt,  dim3(768), dim3(256), 0, stream, Wq, Wk, Wv, wt);
    hipLaunchKernelGGL(proj_qkv, dim3(768), dim3(256), 0, stream, x, enc, wt, qbuf, kbuf, vbuf);
    hipLaunchKernelGGL(attn,     dim3(256), dim3(256), 0, stream, qbuf, kbuf, vbuf, out);
}

// Round 2
// 135.681 us; speedup vs baseline: 1.3270x; 1.3270x over previous
//
#include <hip/hip_runtime.h>
#include <hip/hip_bf16.h>

#define TT 4096
#define SS 4096
#define CC 1024
#define HS 64

typedef __bf16 bf16x8 __attribute__((ext_vector_type(8)));
typedef __bf16 bf16x4 __attribute__((ext_vector_type(4)));
typedef float  f32x4  __attribute__((ext_vector_type(4)));
typedef float  f32x16 __attribute__((ext_vector_type(16)));

#define MFMA16(A,B,C) __builtin_amdgcn_mfma_f32_16x16x32_bf16((A),(B),(C),0,0,0)
#define MFMA32(A,B,C) __builtin_amdgcn_mfma_f32_32x32x16_bf16((A),(B),(C),0,0,0)

__device__ __forceinline__ int pkbf(float a, float b) {
    union { struct { __bf16 lo, hi; } h; int i; } u;
    u.h.lo = (__bf16)a; u.h.hi = (__bf16)b;
    return u.i;
}

// ---------------- prep: W[1024][64] fp32 -> WT[64][1024] bf16 --------------------------
// Wq folded scale = 2^-3 * log2(e)  (softmax done in exp2 domain)
__global__ __launch_bounds__(256) void prep_wt(const float* __restrict__ Wq,
                                               const float* __restrict__ Wk,
                                               const float* __restrict__ Wv,
                                               __bf16* __restrict__ wt) {
    int idx = blockIdx.x * 256 + threadIdx.x;   // 3*65536 total
    int mat = idx >> 16;
    int e   = idx & 65535;
    int d   = e >> 10;
    int kk  = e & 1023;
    const float* W = (mat == 0) ? Wq : (mat == 1 ? Wk : Wv);
    float v = W[kk * HS + d];
    if (mat == 0) v *= 0.125f * 1.44269504088896340736f;
    wt[idx] = (__bf16)v;                        // wt[mat][d][kk]
}

// ---------------- fused QKV projection -------------------------------------------------
// blockIdx [0,256): q from x; [256,512): k AND v (transposed) from enc (enc read once)
__global__ __launch_bounds__(256) void proj_qkv(const float* __restrict__ x,
                                                const float* __restrict__ enc,
                                                const __bf16* __restrict__ wt,
                                                __bf16* __restrict__ qb,
                                                __bf16* __restrict__ kb,
                                                __bf16* __restrict__ vt) {
    __shared__ __bf16 Alds[64 * 56];
    int tid = threadIdx.x;
    int w = tid >> 6, l = tid & 63, lq = l >> 4, lm = l & 15;
    int kv   = blockIdx.x >> 8;
    int row0 = (blockIdx.x & 255) * 64;
    const float*  src = kv ? enc : x;           // [16384][1024]
    const __bf16* wtA = wt + (kv ? HS * CC : 0);
    const __bf16* wtV = wt + 2 * HS * CC;

    int sr = tid >> 2;
    int sc = (tid & 3) * 8;
    const float* srow = src + (size_t)(row0 + sr) * CC + sc;

    f32x4 accA[4], accV[4];
    #pragma unroll
    for (int i = 0; i < 4; i++) { accA[i] = (f32x4){0.f,0.f,0.f,0.f}; accV[i] = (f32x4){0.f,0.f,0.f,0.f}; }

    for (int kk = 0; kk < CC; kk += 32) {
        float4 f0 = *(const float4*)(srow + kk);
        float4 f1 = *(const float4*)(srow + kk + 4);
        bf16x8 a;
        a[0] = (__bf16)f0.x; a[1] = (__bf16)f0.y; a[2] = (__bf16)f0.z; a[3] = (__bf16)f0.w;
        a[4] = (__bf16)f1.x; a[5] = (__bf16)f1.y; a[6] = (__bf16)f1.z; a[7] = (__bf16)f1.w;
        *(bf16x8*)&Alds[sr * 56 + sc] = a;
        __syncthreads();
        bf16x8 af = *(const bf16x8*)&Alds[(w * 16 + lm) * 56 + lq * 8];
        #pragma unroll
        for (int nt = 0; nt < 4; nt++) {
            bf16x8 bA = *(const bf16x8*)(wtA + (size_t)(nt * 16 + lm) * CC + kk + lq * 8);
            accA[nt] = MFMA16(af, bA, accA[nt]);
        }
        if (kv) {
            #pragma unroll
            for (int nt = 0; nt < 4; nt++) {
                bf16x8 bV = *(const bf16x8*)(wtV + (size_t)(nt * 16 + lm) * CC + kk + lq * 8);
                accV[nt] = MFMA16(af, bV, accV[nt]);
            }
        }
        __syncthreads();
    }

    // D layout: col(n=d)=lm, row(m=src row)=lq*4+r
    if (!kv) {
        #pragma unroll
        for (int nt = 0; nt < 4; nt++)
            #pragma unroll
            for (int r = 0; r < 4; r++)
                qb[(size_t)(row0 + w * 16 + lq * 4 + r) * HS + nt * 16 + lm] = (__bf16)accA[nt][r];
    } else {
        #pragma unroll
        for (int nt = 0; nt < 4; nt++)
            #pragma unroll
            for (int r = 0; r < 4; r++)
                kb[(size_t)(row0 + w * 16 + lq * 4 + r) * HS + nt * 16 + lm] = (__bf16)accA[nt][r];
        int rg = row0 + w * 16 + lq * 4;
        int bb = rg >> 12, s = rg & 4095;
        #pragma unroll
        for (int nt = 0; nt < 4; nt++) {
            bf16x4 pk = { (__bf16)accV[nt][0], (__bf16)accV[nt][1],
                          (__bf16)accV[nt][2], (__bf16)accV[nt][3] };
            *(bf16x4*)(vt + ((size_t)bb * HS + nt * 16 + lm) * SS + s) = pk;
        }
    }
}

// ---------------- flash attention, 32x32 MFMA, s-split across 8 waves ------------------
// grid 512 x 512 threads. Block owns 32 q-rows; wave w owns s in [w*512,(w+1)*512).
// No-max softmax (logits tiny); partial (sum exp*v, sum exp) are additive across waves.
__global__ __launch_bounds__(512, 4) void attn(const __bf16* __restrict__ qb,
                                               const __bf16* __restrict__ kb,
                                               const __bf16* __restrict__ vt,
                                               float* __restrict__ out) {
    __shared__ float accbuf[8][2][64][16];
    __shared__ float lsumbuf[8][64];
    int tid = threadIdx.x, w = tid >> 6, l = tid & 63;
    int hi = l >> 5, ln = l & 31;

    // XCD swizzle: blocks resident on one XCD share the same batch b (K/V fits L2)
    int bid = blockIdx.x;
    int swz = (bid & 7) * 64 + (bid >> 3);
    int b = swz >> 7, tb = swz & 127;
    int t0 = tb * 32;

    // Q B-frags: lane n=ln=t, k=d=16*kd+8*hi+j
    const __bf16* qp = qb + ((size_t)(b * TT + t0 + ln)) * HS + hi * 8;
    bf16x8 qf0 = *(const bf16x8*)(qp);
    bf16x8 qf1 = *(const bf16x8*)(qp + 16);
    bf16x8 qf2 = *(const bf16x8*)(qp + 32);
    bf16x8 qf3 = *(const bf16x8*)(qp + 48);

    const __bf16* kp = kb + ((size_t)(b * SS) + w * 512 + ln) * HS + hi * 8;
    const __bf16* vp = vt + ((size_t)b * HS + ln) * SS + w * 512 + hi * 8;

    f32x16 oacc0, oacc1;
    #pragma unroll
    for (int i = 0; i < 16; i++) { oacc0[i] = 0.f; oacc1[i] = 0.f; }
    float lsum = 0.f;

    for (int it = 0; it < 16; ++it) {
        // K A-frags: lane m=ln=s_local, k=d
        bf16x8 ka0 = *(const bf16x8*)(kp);
        bf16x8 ka1 = *(const bf16x8*)(kp + 16);
        bf16x8 ka2 = *(const bf16x8*)(kp + 32);
        bf16x8 ka3 = *(const bf16x8*)(kp + 48);

        f32x16 s;
        #pragma unroll
        for (int i = 0; i < 16; i++) s[i] = 0.f;
        s = MFMA32(ka0, qf0, s);
        s = MFMA32(ka1, qf1, s);
        s = MFMA32(ka2, qf2, s);
        s = MFMA32(ka3, qf3, s);
        // S^T[s_local][t]: t=ln, s_local=(reg&3)+8*(reg>>2)+4*hi

        float p[16];
        #pragma unroll
        for (int i = 0; i < 16; i++) p[i] = __builtin_amdgcn_exp2f(s[i]);
        float l0 = (p[0] + p[1]) + (p[2] + p[3]);
        float l1 = (p[4] + p[5]) + (p[6] + p[7]);
        float l2 = (p[8] + p[9]) + (p[10] + p[11]);
        float l3 = (p[12] + p[13]) + (p[14] + p[15]);
        lsum += (l0 + l1) + (l2 + l3);

        // P^T -> PV B-frags via permlane32_swap (each swap yields TWO frag dwords)
        int d01 = pkbf(p[0],  p[1]),  d23 = pkbf(p[2],  p[3]);
        int d45 = pkbf(p[4],  p[5]),  d67 = pkbf(p[6],  p[7]);
        int e01 = pkbf(p[8],  p[9]),  e23 = pkbf(p[10], p[11]);
        int e45 = pkbf(p[12], p[13]), e67 = pkbf(p[14], p[15]);
        asm("v_permlane32_swap_b32 %0, %1" : "+v"(d01), "+v"(d45));
        asm("v_permlane32_swap_b32 %0, %1" : "+v"(d23), "+v"(d67));
        asm("v_permlane32_swap_b32 %0, %1" : "+v"(e01), "+v"(e45));
        asm("v_permlane32_swap_b32 %0, %1" : "+v"(e23), "+v"(e67));
        union F { int i[4]; bf16x8 v; } f0, f1;
        f0.i[0] = d01; f0.i[1] = d23; f0.i[2] = d45; f0.i[3] = d67;  // k = s_local 0..15
        f1.i[0] = e01; f1.i[1] = e23; f1.i[2] = e45; f1.i[3] = e67;  // k = s_local 16..31

        // V^T A-frags: lane m=ln=d_local, k=s_sub
        bf16x8 va00 = *(const bf16x8*)(vp + it * 32);
        bf16x8 va01 = *(const bf16x8*)(vp + it * 32 + 16);
        bf16x8 va10 = *(const bf16x8*)(vp + 32 * SS + it * 32);
        bf16x8 va11 = *(const bf16x8*)(vp + 32 * SS + it * 32 + 16);
        oacc0 = MFMA32(va00, f0.v, oacc0);
        oacc0 = MFMA32(va01, f1.v, oacc0);
        oacc1 = MFMA32(va10, f0.v, oacc1);
        oacc1 = MFMA32(va11, f1.v, oacc1);

        kp += 32 * HS;
    }

    lsum += __shfl_xor(lsum, 32, 64);   // lanes l and l^32 hold same t=ln

    // ---- cross-wave combine via LDS (XOR-swizzled 16B groups) ----
    union O { f32x16 v; f32x4 q[4]; } o0, o1;
    o0.v = oacc0; o1.v = oacc1;
    #pragma unroll
    for (int g = 0; g < 4; ++g) {
        *(f32x4*)&accbuf[w][0][l][(g ^ (l & 3)) * 4] = o0.q[g];
        *(f32x4*)&accbuf[w][1][l][(g ^ (l & 3)) * 4] = o1.q[g];
    }
    lsumbuf[w][l] = lsum;
    __syncthreads();

    // 512 threads -> 32 t x 16 d-groups; out^T[d][t]: d=dt*32+(reg&3)+8*(reg>>2)+4*hi
    int t_loc = tid >> 4, dgrp = tid & 15;
    int dt = dgrp >> 3, hi2 = dgrp & 1;
    int gb = (dgrp & 7) >> 1;
    int lane2 = hi2 * 32 + t_loc;
    int gx = gb ^ (lane2 & 3);
    f32x4 sum = {0.f, 0.f, 0.f, 0.f};
    float ls = 0.f;
    #pragma unroll
    for (int ww = 0; ww < 8; ++ww) {
        sum += *(const f32x4*)&accbuf[ww][dt][lane2][gx * 4];
        ls  += lsumbuf[ww][t_loc];
    }
    f32x4 o = sum * (1.0f / ls);
    *(f32x4*)(out + (size_t)(b * TT + t0 + t_loc) * HS + dgrp * 4) = o;
}

// ---------------- launcher --------------------------------------------------------------
extern "C" void kernel_launch(void* const* d_in, const int* in_sizes, int n_in,
                              void* d_out, int out_size, void* d_ws, size_t ws_size,
                              hipStream_t stream) {
    (void)in_sizes; (void)n_in; (void)out_size; (void)ws_size;
    const float* x   = (const float*)d_in[0];
    const float* enc = (const float*)d_in[1];
    const float* Wq  = (const float*)d_in[2];
    const float* Wk  = (const float*)d_in[3];
    const float* Wv  = (const float*)d_in[4];
    float* out = (float*)d_out;

    char* ws = (char*)d_ws;
    __bf16* wtb  = (__bf16*)ws;                            // 393216 B
    __bf16* qbuf = (__bf16*)(ws + 393216);                 // 2 MB
    __bf16* kbuf = (__bf16*)(ws + 393216 + 2097152);       // 2 MB
    __bf16* vbuf = (__bf16*)(ws + 393216 + 2 * 2097152);   // 2 MB

    hipLaunchKernelGGL(prep_wt,  dim3(768), dim3(256), 0, stream, Wq, Wk, Wv, wtb);
    hipLaunchKernelGGL(proj_qkv, dim3(512), dim3(256), 0, stream, x, enc, wtb, qbuf, kbuf, vbuf);
    hipLaunchKernelGGL(attn,     dim3(512), dim3(512), 0, stream, qbuf, kbuf, vbuf, out);
}